// Round 2
// baseline (206.106 us; speedup 1.0000x reference)
//
#include <hip/hip_runtime.h>
#include <stdint.h>

typedef __bf16 bf16;
typedef __bf16 bf16x4 __attribute__((ext_vector_type(4)));
typedef __bf16 bf16x8 __attribute__((ext_vector_type(8)));
typedef float f32x4 __attribute__((ext_vector_type(4)));

#define MFMA(a, b, c) __builtin_amdgcn_mfma_f32_16x16x32_bf16(a, b, c, 0, 0, 0)

// ---------------- prep kernels ----------------

__global__ void k_cast_x(const float* __restrict__ x, bf16* __restrict__ xb) {
    int i = (blockIdx.x * 256 + threadIdx.x) * 4;   // grid sized exactly: 2048*256*4 = 2*2048*512
    float4 v = *reinterpret_cast<const float4*>(x + i);
    bf16x4 o = { (bf16)v.x, (bf16)v.y, (bf16)v.z, (bf16)v.w };
    *reinterpret_cast<bf16x4*>(xb + i) = o;
}

// transpose+cast W [512(k)][512(n)] f32 -> WT [512(n)][512(k)] bf16, 4 matrices via z
__global__ void k_prep_w(const float* __restrict__ w0, const float* __restrict__ w1,
                         const float* __restrict__ w2, const float* __restrict__ w3,
                         bf16* __restrict__ o0, bf16* __restrict__ o1,
                         bf16* __restrict__ o2, bf16* __restrict__ o3) {
    __shared__ float t[64][65];
    const float* w; bf16* o;
    if (blockIdx.z == 0)      { w = w0; o = o0; }
    else if (blockIdx.z == 1) { w = w1; o = o1; }
    else if (blockIdx.z == 2) { w = w2; o = o2; }
    else                      { w = w3; o = o3; }
    int n0 = blockIdx.x * 64, k0 = blockIdx.y * 64;
    int tx = threadIdx.x & 63, ty = threadIdx.x >> 6;
    #pragma unroll
    for (int s = 0; s < 16; ++s) {
        int r = ty * 16 + s;
        t[r][tx] = w[(k0 + r) * 512 + n0 + tx];
    }
    __syncthreads();
    #pragma unroll
    for (int s = 0; s < 16; ++s) {
        int r = ty * 16 + s;
        o[(n0 + r) * 512 + k0 + tx] = (bf16)t[tx][r];
    }
}

// Er [2048][64] f32 -> erB [2176][64] bf16, rows >= 2048 zero (land only on masked positions)
__global__ void k_prep_er(const float* __restrict__ er, bf16* __restrict__ erB) {
    int i = blockIdx.x * 256 + threadIdx.x;   // grid exact: 544*256 = 2176*64
    int r = i >> 6;
    erB[i] = (r < 2048) ? (bf16)er[i] : (bf16)0.0f;
}

// ---------------- 64x64 GEMM tile core (A[m][k] bf16 x BT[n][k] bf16, K=512) ----------------

__device__ __forceinline__ void gemm_tile_64x64(
    const bf16* __restrict__ A, const bf16* __restrict__ BT,
    int m0, int n0, bf16* la, bf16* lb, f32x4 (&acc)[4])
{
    const int tid = threadIdx.x;
    const int w = tid >> 6, lane = tid & 63;
    const int fm = lane & 15, fg = lane >> 4;
    const int srow = tid >> 2, sch = tid & 3;
    const int sph = sch ^ ((srow >> 1) & 3);        // 64B-row XOR swizzle (2-way on frag reads)
    for (int kt = 0; kt < 16; ++kt) {
        const int kb = kt * 32;
        __syncthreads();
        *reinterpret_cast<bf16x8*>(&la[srow * 32 + sph * 8]) =
            *reinterpret_cast<const bf16x8*>(&A[(m0 + srow) * 512 + kb + sch * 8]);
        *reinterpret_cast<bf16x8*>(&lb[srow * 32 + sph * 8]) =
            *reinterpret_cast<const bf16x8*>(&BT[(n0 + srow) * 512 + kb + sch * 8]);
        __syncthreads();
        const int ar = w * 16 + fm;
        bf16x8 af = *reinterpret_cast<const bf16x8*>(&la[ar * 32 + (fg ^ ((ar >> 1) & 3)) * 8]);
        #pragma unroll
        for (int c = 0; c < 4; ++c) {
            const int br = c * 16 + fm;
            bf16x8 bb = *reinterpret_cast<const bf16x8*>(&lb[br * 32 + (fg ^ ((br >> 1) & 3)) * 8]);
            acc[c] = MFMA(af, bb, acc[c]);
        }
    }
}

// QKV projection: xb [4096][512] x {WqT,WkT,WvT} -> q,k per-head [bh][2048][64]; v transposed [bh][64][2048]
__global__ __launch_bounds__(256, 2) void k_gemm_qkv(
    const bf16* __restrict__ xb, const bf16* __restrict__ wqT,
    const bf16* __restrict__ wkT, const bf16* __restrict__ wvT,
    bf16* __restrict__ qo, bf16* __restrict__ ko, bf16* __restrict__ vTo)
{
    __shared__ bf16 la[64 * 32];
    __shared__ bf16 lb[64 * 32];
    const int m0 = blockIdx.x * 64, n0 = blockIdx.y * 64, z = blockIdx.z;
    const bf16* BT = (z == 0) ? wqT : (z == 1) ? wkT : wvT;
    f32x4 acc[4] = {};
    gemm_tile_64x64(xb, BT, m0, n0, la, lb, acc);
    const int w = threadIdx.x >> 6, lane = threadIdx.x & 63;
    const int fm = lane & 15, fg = lane >> 4;
    #pragma unroll
    for (int c = 0; c < 4; ++c)
        #pragma unroll
        for (int r = 0; r < 4; ++r) {
            const int m  = m0 + w * 16 + fg * 4 + r;       // global token
            const int nf = n0 + c * 16 + fm;               // feature
            const int b = m >> 11, tok = m & 2047;
            const int h = nf >> 6, d = nf & 63;
            const float v = acc[c][r];
            if (z == 0)      qo[((b * 8 + h) * 2048 + tok) * 64 + d] = (bf16)(v * 0.125f); // fold 1/sqrt(dh)
            else if (z == 1) ko[((b * 8 + h) * 2048 + tok) * 64 + d] = (bf16)v;
            else             vTo[((b * 8 + h) * 64 + d) * 2048 + tok] = (bf16)v;
        }
}

// output projection: ao [4096][512] bf16 x WoT -> out f32
__global__ __launch_bounds__(256, 2) void k_gemm_out(
    const bf16* __restrict__ ao, const bf16* __restrict__ woT, float* __restrict__ out)
{
    __shared__ bf16 la[64 * 32];
    __shared__ bf16 lb[64 * 32];
    const int m0 = blockIdx.x * 64, n0 = blockIdx.y * 64;
    f32x4 acc[4] = {};
    gemm_tile_64x64(ao, woT, m0, n0, la, lb, acc);
    const int w = threadIdx.x >> 6, lane = threadIdx.x & 63;
    const int fm = lane & 15, fg = lane >> 4;
    #pragma unroll
    for (int c = 0; c < 4; ++c)
        #pragma unroll
        for (int r = 0; r < 4; ++r) {
            const int m  = m0 + w * 16 + fg * 4 + r;
            const int nf = n0 + c * 16 + fm;
            out[m * 512 + nf] = acc[c][r];
        }
}

// ---------------- fused causal flash attention with relative bias ----------------
// grid (32 qtiles, 16 bh), 256 threads (4 waves), wave w owns rows [16w,16w+16) of the 64-row Q tile.
__global__ __launch_bounds__(256, 2) void k_attn(
    const bf16* __restrict__ qg, const bf16* __restrict__ kg,
    const bf16* __restrict__ vg, const bf16* __restrict__ erB,
    bf16* __restrict__ ao)
{
    __shared__ bf16 lk[64 * 64];    // K tile  [j][d], XOR-swizzled 16B chunks
    __shared__ bf16 lv[64 * 64];    // V^T tile [d][j], swizzled
    __shared__ bf16 ler[128 * 64];  // Er band [t][d], swizzled
    __shared__ float gt[128 * 68];  // G^T [t][il], stride 68 (pad)
    __shared__ bf16 lp[64 * 64];    // P [i][j] bf16, swizzled

    const int qt = 31 - blockIdx.x;          // heavy tiles dispatched first
    const int bh = blockIdx.y;
    const int i0 = qt * 64;
    const bf16* qp = qg + bh * 2048 * 64;
    const bf16* kp = kg + bh * 2048 * 64;
    const bf16* vp = vg + bh * 64 * 2048;

    const int tid = threadIdx.x;
    const int w = tid >> 6, lane = tid & 63;
    const int fm = lane & 15, fg = lane >> 4;

    // Q fragments for this wave's 16 rows (q already scaled by 1/8)
    const bf16x8 aq0 = *reinterpret_cast<const bf16x8*>(&qp[(i0 + w * 16 + fm) * 64 + fg * 8]);
    const bf16x8 aq1 = *reinterpret_cast<const bf16x8*>(&qp[(i0 + w * 16 + fm) * 64 + 32 + fg * 8]);

    f32x4 oacc[4] = {};
    float mrow[4] = { -1e30f, -1e30f, -1e30f, -1e30f };
    float lrow[4] = { 0.f, 0.f, 0.f, 0.f };

    for (int j0 = 0; j0 <= i0; j0 += 64) {
        __syncthreads();                      // protect LDS from previous iteration's readers
        const int m0e = 1984 - i0 + j0;       // Er band start = (N-1)-(i0+63)+j0
        #pragma unroll
        for (int t = 0; t < 2; ++t) {
            int cid = tid + t * 256;
            int row = cid >> 3, g = cid & 7, ph = g ^ (row & 7);
            *reinterpret_cast<bf16x8*>(&lk[row * 64 + ph * 8]) =
                *reinterpret_cast<const bf16x8*>(&kp[(j0 + row) * 64 + g * 8]);
            *reinterpret_cast<bf16x8*>(&lv[row * 64 + ph * 8]) =
                *reinterpret_cast<const bf16x8*>(&vp[row * 2048 + j0 + g * 8]);
        }
        #pragma unroll
        for (int t = 0; t < 4; ++t) {
            int cid = tid + t * 256;
            int row = cid >> 3, g = cid & 7, ph = g ^ (row & 7);
            *reinterpret_cast<bf16x8*>(&ler[row * 64 + ph * 8]) =
                *reinterpret_cast<const bf16x8*>(&erB[(m0e + row) * 64 + g * 8]);
        }
        __syncthreads();

        // S = Q K^T  (wave strip 16x64)
        f32x4 sa[4];
        #pragma unroll
        for (int c = 0; c < 4; ++c) {
            const int br = c * 16 + fm;
            bf16x8 b0 = *reinterpret_cast<const bf16x8*>(&lk[br * 64 + ((fg     ^ (br & 7)) * 8)]);
            bf16x8 b1 = *reinterpret_cast<const bf16x8*>(&lk[br * 64 + (((4+fg) ^ (br & 7)) * 8)]);
            f32x4 s = {};
            s = MFMA(aq0, b0, s);
            s = MFMA(aq1, b1, s);
            sa[c] = s;
        }
        // G = Q ErBand^T (16x128), stored transposed in LDS: gt[t][il]
        #pragma unroll
        for (int cf = 0; cf < 8; ++cf) {
            const int tr = cf * 16 + fm;
            bf16x8 b0 = *reinterpret_cast<const bf16x8*>(&ler[tr * 64 + ((fg     ^ (tr & 7)) * 8)]);
            bf16x8 b1 = *reinterpret_cast<const bf16x8*>(&ler[tr * 64 + (((4+fg) ^ (tr & 7)) * 8)]);
            f32x4 g = {};
            g = MFMA(aq0, b0, g);
            g = MFMA(aq1, b1, g);
            *reinterpret_cast<f32x4*>(&gt[tr * 68 + w * 16 + fg * 4]) = g;   // same-wave columns only
        }

        // rel gather + causal mask + tile row-max
        const int dmax = i0 - j0;
        float mtile[4] = { -3e38f, -3e38f, -3e38f, -3e38f };
        #pragma unroll
        for (int c = 0; c < 4; ++c)
            #pragma unroll
            for (int r = 0; r < 4; ++r) {
                const int il = w * 16 + fg * 4 + r;
                const int jl = c * 16 + fm;
                float s = sa[c][r] + gt[(63 - il + jl) * 68 + il];
                if (jl - il > dmax) s = -3e38f;
                sa[c][r] = s;
                mtile[r] = fmaxf(mtile[r], s);
            }
        // online softmax stats (reduce across the 16-lane col group)
        float fac[4];
        #pragma unroll
        for (int r = 0; r < 4; ++r) {
            float v = mtile[r];
            v = fmaxf(v, __shfl_xor(v, 1, 64));
            v = fmaxf(v, __shfl_xor(v, 2, 64));
            v = fmaxf(v, __shfl_xor(v, 4, 64));
            v = fmaxf(v, __shfl_xor(v, 8, 64));
            const float mn = fmaxf(mrow[r], v);
            fac[r] = __expf(mrow[r] - mn);
            mrow[r] = mn;
        }
        float rs[4] = { 0.f, 0.f, 0.f, 0.f };
        #pragma unroll
        for (int c = 0; c < 4; ++c)
            #pragma unroll
            for (int r = 0; r < 4; ++r) {
                const float p = __expf(sa[c][r] - mrow[r]);
                rs[r] += p;
                const int il = w * 16 + fg * 4 + r;
                const int jl = c * 16 + fm;
                lp[il * 64 + ((((jl >> 3) ^ (il & 7)) << 3) | (jl & 7))] = (bf16)p;
            }
        #pragma unroll
        for (int r = 0; r < 4; ++r) {
            float v = rs[r];
            v += __shfl_xor(v, 1, 64);
            v += __shfl_xor(v, 2, 64);
            v += __shfl_xor(v, 4, 64);
            v += __shfl_xor(v, 8, 64);
            lrow[r] = lrow[r] * fac[r] + v;
        }
        #pragma unroll
        for (int df = 0; df < 4; ++df)
            #pragma unroll
            for (int r = 0; r < 4; ++r)
                oacc[df][r] *= fac[r];
        // O += P V  (P from LDS, same-wave rows: no barrier needed)
        const int ar = w * 16 + fm;
        bf16x8 ap0 = *reinterpret_cast<const bf16x8*>(&lp[ar * 64 + ((fg     ^ (ar & 7)) * 8)]);
        bf16x8 ap1 = *reinterpret_cast<const bf16x8*>(&lp[ar * 64 + (((4+fg) ^ (ar & 7)) * 8)]);
        #pragma unroll
        for (int df = 0; df < 4; ++df) {
            const int dr = df * 16 + fm;
            bf16x8 b0 = *reinterpret_cast<const bf16x8*>(&lv[dr * 64 + ((fg     ^ (dr & 7)) * 8)]);
            bf16x8 b1 = *reinterpret_cast<const bf16x8*>(&lv[dr * 64 + (((4+fg) ^ (dr & 7)) * 8)]);
            oacc[df] = MFMA(ap0, b0, oacc[df]);
            oacc[df] = MFMA(ap1, b1, oacc[df]);
        }
    }

    // epilogue: ao[b][i][h*64+d]
    const int b = bh >> 3, h = bh & 7;
    #pragma unroll
    for (int df = 0; df < 4; ++df)
        #pragma unroll
        for (int r = 0; r < 4; ++r) {
            const int i = i0 + w * 16 + fg * 4 + r;
            const int d = df * 16 + fm;
            ao[(b * 2048 + i) * 512 + h * 64 + d] = (bf16)(oacc[df][r] / lrow[r]);
        }
}

// ---------------- host launcher ----------------

extern "C" void kernel_launch(void* const* d_in, const int* in_sizes, int n_in,
                              void* d_out, int out_size, void* d_ws, size_t ws_size,
                              hipStream_t stream) {
    (void)in_sizes; (void)n_in; (void)out_size; (void)ws_size;
    const float* x  = (const float*)d_in[0];
    const float* Wq = (const float*)d_in[1];
    const float* Wk = (const float*)d_in[2];
    const float* Wv = (const float*)d_in[3];
    const float* Wo = (const float*)d_in[4];
    const float* Er = (const float*)d_in[5];
    float* out = (float*)d_out;

    char* ws = (char*)d_ws;
    bf16* xb  = (bf16*)(ws);                  // 4096*512        = 4,194,304 B
    bf16* wqT = (bf16*)(ws + 4194304);        // 512*512*2       =   524,288 B
    bf16* wkT = (bf16*)(ws + 4718592);
    bf16* wvT = (bf16*)(ws + 5242880);
    bf16* woT = (bf16*)(ws + 5767168);
    bf16* erB = (bf16*)(ws + 6291456);        // 2176*64*2       =   278,528 B
    bf16* q   = (bf16*)(ws + 6569984);        // 16*2048*64*2    = 4,194,304 B
    bf16* k   = (bf16*)(ws + 10764288);
    bf16* vT  = (bf16*)(ws + 14958592);
    bf16* ao  = (bf16*)(ws + 19152896);       // end 23,347,200 B

    k_cast_x<<<dim3(2048), dim3(256), 0, stream>>>(x, xb);
    k_prep_w<<<dim3(8, 8, 4), dim3(256), 0, stream>>>(Wq, Wk, Wv, Wo, wqT, wkT, wvT, woT);
    k_prep_er<<<dim3(544), dim3(256), 0, stream>>>(Er, erB);
    k_gemm_qkv<<<dim3(64, 8, 3), dim3(256), 0, stream>>>(xb, wqT, wkT, wvT, q, k, vT);
    k_attn<<<dim3(32, 16), dim3(256), 0, stream>>>(q, k, vT, erB, ao);
    k_gemm_out<<<dim3(64, 8), dim3(256), 0, stream>>>(ao, woT, out);
}